// Round 15
// baseline (207.476 us; speedup 1.0000x reference)
//
#include <hip/hip_runtime.h>
#include <hip/hip_bf16.h>

// Geometry constants
#define NPHI 720
#define NT   512
#define NH   256
#define NB   32

#define DPHI_F   0.004363323129985824f   // pi/720
#define INV_DT_F 181.01933598375618f     // 256/sqrt(2)
#define DX_F     0.0078125f              // 2/256
#define W2PI_F   0.012271846303085130f   // 2*pi/512

#define FSTR 520   // padded filt row stride (4 zero | 512 data | 4 zero)

typedef __fp16  h2   __attribute__((ext_vector_type(2)));   // cvt_pkrtz return type
typedef _Float16 f16x2 __attribute__((ext_vector_type(2))); // fdot2 operand type
typedef _Float16 f16x8 __attribute__((ext_vector_type(8))); // mfma A/B operand
typedef float    f32x4 __attribute__((ext_vector_type(4))); // mfma C/D
typedef float    f32x4u __attribute__((ext_vector_type(4), aligned(4)));
typedef float    f32x2u __attribute__((ext_vector_type(2), aligned(4)));

__device__ __forceinline__ float fdot2f(h2 a, float b_bits, float c) {
    return __builtin_amdgcn_fdot2(__builtin_bit_cast(f16x2, a),
                                  __builtin_bit_cast(f16x2, b_bits), c, false);
}

// ---------------------------------------------------------------------------
// Setup kernel (single dispatch):
//  blocks [0,64):    Ht[o][m] = h[(o-m)&511] fp16 pairs (h computed locally)
//  blocks [64,67):   trig table -> ws[512 + 4p ..]
//  blocks [67,195):  zero out (float4 grid-stride)
//  blocks [195,323): zero filt row pads ([0,4) and [516,520) of each row)
// ---------------------------------------------------------------------------
__global__ __launch_bounds__(256) void setup_kernel(const float* __restrict__ kern,
                                                    float* __restrict__ ws,
                                                    unsigned int* __restrict__ Ht,
                                                    float4* __restrict__ out4,
                                                    float* __restrict__ filt) {
    const int bid = (int)blockIdx.x;
    const int tid = threadIdx.x;
    if (bid < 64) {
        __shared__ float ctab[512];
        __shared__ float kk[257];
        __shared__ float hloc[512];
        kk[tid] = kern[tid];
        if (tid == 0) kk[256] = kern[256];
        ctab[tid]       = cosf((float)tid * W2PI_F);
        ctab[tid + 256] = cosf((float)(tid + 256) * W2PI_F);
        __syncthreads();
        for (int tt = tid; tt < 512; tt += 256) {
            float acc = 0.f;
            for (int k = 1; k < 256; ++k)
                acc += kk[k] * ctab[(k * tt) & 511];
            hloc[tt] = (kk[0] + ((tt & 1) ? -kk[256] : kk[256]) + 2.f * acc) * (1.f / 512.f);
        }
        __syncthreads();
        const int o  = bid * 8 + (tid >> 5);
        const int c0 = tid & 31;
        unsigned int* dst = Ht + (size_t)o * 256;
        #pragma unroll
        for (int k = 0; k < 8; ++k) {
            int mp = c0 + 32 * k;
            h2 p = __builtin_amdgcn_cvt_pkrtz(hloc[(o - 2 * mp) & 511],
                                              hloc[(o - 2 * mp - 1) & 511]);
            dst[mp] = __builtin_bit_cast(unsigned int, p);
        }
    } else if (bid < 67) {
        int p = (bid - 64) * 256 + tid;
        if (p < NPHI) {
            float ang = ((float)p + 0.5f) * DPHI_F;
            float s, c;
            sincosf(ang, &s, &c);
            float cd = c * INV_DT_F;
            float sd = s * INV_DT_F;
            ws[512 + 4 * p + 0] = cd;
            ws[512 + 4 * p + 1] = sd;
            ws[512 + 4 * p + 2] = cd * DX_F;
            ws[512 + 4 * p + 3] = sd * DX_F;
        }
    } else if (bid < 195) {
        const float4 z = make_float4(0.f, 0.f, 0.f, 0.f);
        const int nout4 = NB * NH * NH / 4;
        for (int i = (bid - 67) * 256 + tid; i < nout4; i += 128 * 256)
            out4[i] = z;
    } else {
        const float4 z = make_float4(0.f, 0.f, 0.f, 0.f);
        const int rb = (bid - 195) * 180;           // 23040 / 128 = 180 rows/block
        for (int i = tid; i < 360; i += 256) {
            int row = rb + (i >> 1);
            float* p = filt + (size_t)row * FSTR + ((i & 1) ? 516 : 0);
            *(float4*)p = z;
        }
    }
}

// ---------------------------------------------------------------------------
// Kernel B: filtering as GEMM on matrix cores (R14-measured, verbatim).
// Tile 64(M) x 512(N) x 32(K); 512 threads = 8 waves; 360 blocks.
// ---------------------------------------------------------------------------
#define ASTR 40
#define BSTR 40

__global__ __launch_bounds__(512) void conv_gemm_kernel(const float* __restrict__ g,
                                                        const unsigned short* __restrict__ Ht,
                                                        float* __restrict__ filt) {
    __shared__ __attribute__((aligned(16))) unsigned short As[64 * ASTR];
    __shared__ __attribute__((aligned(16))) unsigned short Bs[512 * BSTR];
    const int tid = threadIdx.x;
    const int m0 = (int)blockIdx.x * 64;

    const int w = tid >> 6, l = tid & 63;
    const int wm = (w >> 2) * 32;          // 0 or 32
    const int wn = (w & 3) * 128;          // 0,128,256,384
    const int fr = l & 15, g16 = l >> 4;

    const int arow = tid >> 3, aq = (tid & 7) * 4;   // A staging: 8 thr/row, float4 each

    f32x4 acc[2][8];
    #pragma unroll
    for (int i = 0; i < 2; ++i)
        #pragma unroll
        for (int j = 0; j < 8; ++j) acc[i][j] = (f32x4){0.f, 0.f, 0.f, 0.f};

    for (int k0 = 0; k0 < 512; k0 += 32) {
        __syncthreads();
        {   // stage A: 64 rows x 32 fp16
            const float* src = g + (size_t)(m0 + arow) * NT + (k0 + aq);
            float4 v = *(const float4*)src;
            h2 p0 = __builtin_amdgcn_cvt_pkrtz(v.x, v.y);
            h2 p1 = __builtin_amdgcn_cvt_pkrtz(v.z, v.w);
            *(uint2*)&As[arow * ASTR + aq] =
                make_uint2(__builtin_bit_cast(unsigned int, p0),
                           __builtin_bit_cast(unsigned int, p1));
        }
        {   // stage B: 512 rows x 32 fp16, 1 row per thread (64B)
            const float4* src = (const float4*)(Ht + (size_t)tid * NT + k0);
            float4 v0 = src[0], v1 = src[1], v2 = src[2], v3 = src[3];
            unsigned short* dst = &Bs[tid * BSTR];
            *(float4*)(dst)      = v0;
            *(float4*)(dst + 8)  = v1;
            *(float4*)(dst + 16) = v2;
            *(float4*)(dst + 24) = v3;
        }
        __syncthreads();

        f16x8 af[2], bf[8];
        #pragma unroll
        for (int i = 0; i < 2; ++i)
            af[i] = *(const f16x8*)&As[(wm + i * 16 + fr) * ASTR + g16 * 8];
        #pragma unroll
        for (int j = 0; j < 8; ++j)
            bf[j] = *(const f16x8*)&Bs[(wn + j * 16 + fr) * BSTR + g16 * 8];
        #pragma unroll
        for (int i = 0; i < 2; ++i)
            #pragma unroll
            for (int j = 0; j < 8; ++j)
                acc[i][j] = __builtin_amdgcn_mfma_f32_16x16x32_f16(af[i], bf[j], acc[i][j], 0, 0, 0);
    }

    #pragma unroll
    for (int i = 0; i < 2; ++i)
        #pragma unroll
        for (int j = 0; j < 8; ++j)
            #pragma unroll
            for (int v = 0; v < 4; ++v) {
                int row = m0 + wm + i * 16 + g16 * 4 + v;
                int col = wn + j * 16 + fr;
                filt[(size_t)row * FSTR + 4 + col] = acc[i][j][v];
            }
}

// ---------------------------------------------------------------------------
// Kernel C: backprojection v9 -- split 8B half-slot windows, 2x ds_read_b64.
// win01[a][s] = {b0lo,b0hi,b1lo,b1hi} fp16 (8B); win23 same for batches 2,3
// in a separate region at compile-time offset -> second read uses offset:
// immediate, no extra address math.  b64 gather spread = 32 slots x 2 banks
// -> 2 lanes/bank (free, m136) -- removes the b128 4-way conflict tax.
// Everything else (index math, staging loads, fdot2 compute) = R13/R14.
// Grid = 4 quarters x 8 batch-quads x 64 tiles = 2048 blocks (8/CU).
// Index convention (R1/R3/R4-verified): ip = floor(q + cst), cst = 256.5-b0.
// ---------------------------------------------------------------------------
#define WCHUNK 15
#define WSTR   82

__global__ __launch_bounds__(256, 8) void backproject_kernel(const float* __restrict__ filt,
                                                             const float* __restrict__ ws,
                                                             float* __restrict__ out) {
    __shared__ __attribute__((aligned(16))) float2 win01[WCHUNK * WSTR];
    __shared__ __attribute__((aligned(16))) float2 win23[WCHUNK * WSTR];
    __shared__ float cstbuf[WCHUNK];

    const int tid  = threadIdx.x;
    const int bidx = (int)blockIdx.x;
    const int quarter = bidx >> 9;         // 0..3: angle range
    const int rem  = bidx & 511;
    const int b    = (rem >> 6) * 4;       // batches b .. b+3
    const int tile = rem & 63;             // 8 x 8 tiles of 32x32
    const int i0 = (tile >> 3) * 32;
    const int j0 = (tile & 7) * 32;

    const float* trig = ws + 512;

    // compute-phase pixel mapping: wave = 16x16 px, lane = 2x2 px patch
    const int w  = tid >> 6;
    const int l  = tid & 63;
    const int wi = (w >> 1) * 16, wj = (w & 1) * 16;
    const int li = l >> 3, lj = l & 7;
    const int pi = i0 + wi + 2 * li;
    const int pj = j0 + wj + 2 * lj;
    const float xi = -1.f + ((float)pi + 0.5f) * DX_F;
    const float yj = -1.f + ((float)pj + 0.5f) * DX_F;

    // staging mapping: 16 threads per angle (st < 14 active), sa in [0,15)
    const int sa = tid >> 4;
    const int st = tid & 15;
    const float xlo = -1.f + ((float)i0 + 0.5f) * DX_F;
    const float xhi = xlo + 31.f * DX_F;
    const float ylo = -1.f + ((float)j0 + 0.5f) * DX_F;
    const float yhi = ylo + 31.f * DX_F;

    const float* fb0 = filt + (size_t)b * (NPHI * FSTR);

    float acc[4][2][2];
    #pragma unroll
    for (int bb = 0; bb < 4; ++bb)
        #pragma unroll
        for (int di = 0; di < 2; ++di)
            #pragma unroll
            for (int dj = 0; dj < 2; ++dj) acc[bb][di][dj] = 0.f;

    const int pbeg = quarter * 180;
    for (int p0 = pbeg; p0 < pbeg + 180; p0 += WCHUNK) {
        __syncthreads();
        if (sa < WCHUNK && st < 14) {
            const int p = p0 + sa;
            const float4 tg = *(const float4*)&trig[p * 4];
            const float umin = 256.5f + fminf(xlo * tg.x, xhi * tg.x)
                                      + fminf(ylo * tg.y, yhi * tg.y);
            const float b0f = floorf(umin) - 1.f;
            if (st == 0) cstbuf[sa] = 256.5f - b0f;
            const int b0 = (int)b0f;
            const int base  = b0 + 5 * st - 1;
            const int basec = min(base, 506);
            float f[4][6];
            #pragma unroll
            for (int bb = 0; bb < 4; ++bb) {
                const float* rr = fb0 + (size_t)bb * (NPHI * FSTR) + (size_t)p * FSTR + 4 + basec;
                f32x4u v0 = *(const f32x4u*)rr;
                f32x2u v1 = *(const f32x2u*)(rr + 4);
                f[bb][0] = v0[0]; f[bb][1] = v0[1]; f[bb][2] = v0[2];
                f[bb][3] = v0[3]; f[bb][4] = v1[0]; f[bb][5] = v1[1];
            }
            const int s0 = sa * WSTR + (basec - b0 + 1);
            #pragma unroll
            for (int j = 0; j < 5; ++j) {
                h2 a0 = __builtin_amdgcn_cvt_pkrtz(f[0][j], f[0][j + 1]);
                h2 a1 = __builtin_amdgcn_cvt_pkrtz(f[1][j], f[1][j + 1]);
                h2 a2 = __builtin_amdgcn_cvt_pkrtz(f[2][j], f[2][j + 1]);
                h2 a3 = __builtin_amdgcn_cvt_pkrtz(f[3][j], f[3][j + 1]);
                win01[s0 + j] = make_float2(__builtin_bit_cast(float, a0),
                                            __builtin_bit_cast(float, a1));
                win23[s0 + j] = make_float2(__builtin_bit_cast(float, a2),
                                            __builtin_bit_cast(float, a3));
            }
        }
        __syncthreads();

        #pragma unroll 3
        for (int a = 0; a < WCHUNK; ++a) {
            const float4 tg = *(const float4*)&trig[(p0 + a) * 4]; // cd,sd,dci,dsj
            const float cst = cstbuf[a];
            const float2* wr01 = &win01[a * WSTR];
            const float2* wr23 = &win23[a * WSTR];
            const float u00 = xi * tg.x + yj * tg.y + cst;
            #pragma unroll
            for (int di = 0; di < 2; ++di) {
                float u = di ? (u00 + tg.z) : u00;
                #pragma unroll
                for (int dj = 0; dj < 2; ++dj) {
                    float fl = floorf(u);
                    float wv = u - fl;
                    int  ip  = (int)fl;
                    h2   wp  = __builtin_amdgcn_cvt_pkrtz(1.f - wv, wv);
                    float2 s01 = wr01[ip];
                    float2 s23 = wr23[ip];
                    acc[0][di][dj] = fdot2f(wp, s01.x, acc[0][di][dj]);
                    acc[1][di][dj] = fdot2f(wp, s01.y, acc[1][di][dj]);
                    acc[2][di][dj] = fdot2f(wp, s23.x, acc[2][di][dj]);
                    acc[3][di][dj] = fdot2f(wp, s23.y, acc[3][di][dj]);
                    u += tg.w;
                }
            }
        }
    }

    #pragma unroll
    for (int bb = 0; bb < 4; ++bb) {
        float* ob = out + (size_t)(b + bb) * (NH * NH) + (size_t)pi * NH + pj;
        #pragma unroll
        for (int di = 0; di < 2; ++di)
            #pragma unroll
            for (int dj = 0; dj < 2; ++dj)
                unsafeAtomicAdd(ob + di * NH + dj, acc[bb][di][dj] * DPHI_F);
    }
}

// ---------------------------------------------------------------------------
extern "C" void kernel_launch(void* const* d_in, const int* in_sizes, int n_in,
                              void* d_out, int out_size, void* d_ws, size_t ws_size,
                              hipStream_t stream) {
    const float* sinos = (const float*)d_in[0];   // [32,720,512] f32
    const float* kern  = (const float*)d_in[1];   // [257] f32
    float* out = (float*)d_out;                   // [32,256,256] f32
    float* ws  = (float*)d_ws;

    // ws layout: [0,4096) f32 tables; [4096, +131072) Ht fp16 (512KB);
    // then padded filt f32 (23040 x 520 floats = 47.9MB).
    unsigned int*   Ht32 = (unsigned int*)(ws + 4096);
    unsigned short* Ht   = (unsigned short*)Ht32;
    float*          filt = ws + 4096 + 131072;

    hipLaunchKernelGGL(setup_kernel, dim3(323), dim3(256), 0, stream,
                       kern, ws, Ht32, (float4*)out, filt);
    hipLaunchKernelGGL(conv_gemm_kernel, dim3(23040 / 64), dim3(512), 0, stream,
                       sinos, Ht, filt);
    hipLaunchKernelGGL(backproject_kernel, dim3(4 * (NB / 4) * 64), dim3(256), 0, stream,
                       filt, ws, out);
}

// Round 16
// 198.097 us; speedup vs baseline: 1.0473x; 1.0473x over previous
//
#include <hip/hip_runtime.h>
#include <hip/hip_bf16.h>

// Geometry constants
#define NPHI 720
#define NT   512
#define NH   256
#define NB   32

#define DPHI_F   0.004363323129985824f   // pi/720
#define INV_DT_F 181.01933598375618f     // 256/sqrt(2)
#define DX_F     0.0078125f              // 2/256
#define W2PI_F   0.012271846303085130f   // 2*pi/512

#define FSTR 520   // padded filt row stride (4 zero | 512 data | 4 zero)

typedef __fp16  h2   __attribute__((ext_vector_type(2)));   // cvt_pkrtz return type
typedef _Float16 f16x2 __attribute__((ext_vector_type(2))); // fdot2 operand type
typedef _Float16 f16x8 __attribute__((ext_vector_type(8))); // mfma A/B operand
typedef float    f32x4 __attribute__((ext_vector_type(4))); // mfma C/D
typedef float    f32x4u __attribute__((ext_vector_type(4), aligned(4)));
typedef float    f32x2u __attribute__((ext_vector_type(2), aligned(4)));

__device__ __forceinline__ float fdot2f(h2 a, float b_bits, float c) {
    return __builtin_amdgcn_fdot2(__builtin_bit_cast(f16x2, a),
                                  __builtin_bit_cast(f16x2, b_bits), c, false);
}

// ---------------------------------------------------------------------------
// Front kernel (single dispatch): GEMM filtering + all setup.
//  blocks [0,360):   GEMM 64(M) x 512(N) x 32(K), circulant B built ONCE in
//                    LDS from locally-computed h (no Ht, no per-step B stage):
//                    Bs[d][kk] = h[(d-kk)&511]; at step k0, B-frag row for
//                    column n is (n-k0)&511.  A staged per step as before.
//                    ctab/kk alias As/Bs during the h prologue (sync-guarded).
//  blocks [360,362): trig table -> ws[512 + 4p ..]
//  blocks [362,426): zero out (float4 grid-stride)
//  blocks [426,490): zero filt row pads (cols [0,4) and [516,520))
// ---------------------------------------------------------------------------
#define ASTR 40
#define BSTR 40

__global__ __launch_bounds__(512) void front_kernel(const float* __restrict__ g,
                                                    const float* __restrict__ kern,
                                                    float* __restrict__ ws,
                                                    float4* __restrict__ out4,
                                                    float* __restrict__ filt) {
    __shared__ __attribute__((aligned(16))) unsigned short As[64 * ASTR];   // 5.12 KB
    __shared__ __attribute__((aligned(16))) unsigned short Bs[512 * BSTR];  // 40 KB
    __shared__ float hloc[512];
    const int bid = (int)blockIdx.x;
    const int tid = threadIdx.x;

    if (bid < 360) {
        // ---- prologue: h = irfft(K,512), then circulant Bs (once) ----
        float* ctab = (float*)As;        // 2 KB alias, dead after prologue
        float* kkp  = (float*)Bs;        // 1 KB alias, dead after prologue
        if (tid < 257) kkp[tid] = kern[tid];
        ctab[tid] = cosf((float)tid * W2PI_F);
        __syncthreads();
        {
            float acc = 0.f;
            for (int k = 1; k < 256; ++k)
                acc += kkp[k] * ctab[(k * tid) & 511];
            hloc[tid] = (kkp[0] + ((tid & 1) ? -kkp[256] : kkp[256]) + 2.f * acc)
                        * (1.f / 512.f);
        }
        __syncthreads();
        {   // Bs row d = tid: Bs[d][m] = h[(d-m)&511], packed fp16 pairs
            unsigned int uu[16];
            #pragma unroll
            for (int q = 0; q < 16; ++q) {
                float lo = hloc[(tid - 2 * q) & 511];
                float hi = hloc[(tid - 2 * q - 1) & 511];
                h2 p = __builtin_amdgcn_cvt_pkrtz(lo, hi);
                uu[q] = __builtin_bit_cast(unsigned int, p);
            }
            unsigned int* dst = (unsigned int*)&Bs[tid * BSTR];
            *(uint4*)(dst)      = make_uint4(uu[0], uu[1], uu[2], uu[3]);
            *(uint4*)(dst + 4)  = make_uint4(uu[4], uu[5], uu[6], uu[7]);
            *(uint4*)(dst + 8)  = make_uint4(uu[8], uu[9], uu[10], uu[11]);
            *(uint4*)(dst + 12) = make_uint4(uu[12], uu[13], uu[14], uu[15]);
        }

        // ---- GEMM ----
        const int m0 = bid * 64;
        const int w = tid >> 6, l = tid & 63;
        const int wm = (w >> 2) * 32;          // 0 or 32
        const int wn = (w & 3) * 128;          // 0,128,256,384
        const int fr = l & 15, g16 = l >> 4;
        const int arow = tid >> 3, aq = (tid & 7) * 4;

        f32x4 acc[2][8];
        #pragma unroll
        for (int i = 0; i < 2; ++i)
            #pragma unroll
            for (int j = 0; j < 8; ++j) acc[i][j] = (f32x4){0.f, 0.f, 0.f, 0.f};

        for (int k0 = 0; k0 < 512; k0 += 32) {
            __syncthreads();   // As free (first iter: prologue aliases done)
            {   // stage A: 64 rows x 32 fp16
                const float* src = g + (size_t)(m0 + arow) * NT + (k0 + aq);
                float4 v = *(const float4*)src;
                h2 p0 = __builtin_amdgcn_cvt_pkrtz(v.x, v.y);
                h2 p1 = __builtin_amdgcn_cvt_pkrtz(v.z, v.w);
                *(uint2*)&As[arow * ASTR + aq] =
                    make_uint2(__builtin_bit_cast(unsigned int, p0),
                               __builtin_bit_cast(unsigned int, p1));
            }
            __syncthreads();

            f16x8 af[2], bf[8];
            #pragma unroll
            for (int i = 0; i < 2; ++i)
                af[i] = *(const f16x8*)&As[(wm + i * 16 + fr) * ASTR + g16 * 8];
            const int rbase = (wn + fr - k0) & 511;
            #pragma unroll
            for (int j = 0; j < 8; ++j) {
                const int row = (rbase + j * 16) & 511;
                bf[j] = *(const f16x8*)&Bs[row * BSTR + g16 * 8];
            }
            #pragma unroll
            for (int i = 0; i < 2; ++i)
                #pragma unroll
                for (int j = 0; j < 8; ++j)
                    acc[i][j] = __builtin_amdgcn_mfma_f32_16x16x32_f16(af[i], bf[j], acc[i][j], 0, 0, 0);
        }

        #pragma unroll
        for (int i = 0; i < 2; ++i)
            #pragma unroll
            for (int j = 0; j < 8; ++j)
                #pragma unroll
                for (int v = 0; v < 4; ++v) {
                    int row = m0 + wm + i * 16 + g16 * 4 + v;
                    int col = wn + j * 16 + fr;
                    filt[(size_t)row * FSTR + 4 + col] = acc[i][j][v];
                }
    } else if (bid < 362) {
        int p = (bid - 360) * 512 + tid;
        if (p < NPHI) {
            float ang = ((float)p + 0.5f) * DPHI_F;
            float s, c;
            sincosf(ang, &s, &c);
            float cd = c * INV_DT_F;
            float sd = s * INV_DT_F;
            ws[512 + 4 * p + 0] = cd;
            ws[512 + 4 * p + 1] = sd;
            ws[512 + 4 * p + 2] = cd * DX_F;
            ws[512 + 4 * p + 3] = sd * DX_F;
        }
    } else if (bid < 426) {
        const float4 z = make_float4(0.f, 0.f, 0.f, 0.f);
        const int nout4 = NB * NH * NH / 4;            // 524288
        for (int i = (bid - 362) * 512 + tid; i < nout4; i += 64 * 512)
            out4[i] = z;
    } else {
        const float4 z = make_float4(0.f, 0.f, 0.f, 0.f);
        const int nslots = 23040 * 2;                  // 46080
        for (int i = (bid - 426) * 512 + tid; i < nslots; i += 64 * 512) {
            int row = i >> 1;
            float* p = filt + (size_t)row * FSTR + ((i & 1) ? 516 : 0);
            *(float4*)p = z;
        }
    }
}

// ---------------------------------------------------------------------------
// Kernel C: backprojection v10 -- 8 batches per block, 4 half-slot regions.
// Grid = 6 angle-sixths x 4 batch-octs x 64 tiles = 1536 blocks (exactly
// 6/CU: LDS 26.3KB; 24 waves/CU).  Each block: 120 angles, chunks of 10.
// win[pp][a*WSTR+s] = {lo,hi of batch 2pp | lo,hi of batch 2pp+1} fp16 (8B);
// one address serves 4 ds_read_b64 (regions at compile-time offsets) = 8
// samples -> VALU/sample 2.75 -> 1.875.  b64 spread = 2 lanes/bank (free).
// Staging halves (8 batches x 120 angles per block).
// Sixths combine via unsafeAtomicAdd onto zeroed out (6 addends/pixel).
// Index convention (R1/R3/R4-verified): ip = floor(q + cst), cst = 256.5-b0.
// ---------------------------------------------------------------------------
#define WCHUNK 10
#define WSTR   82
#define WREG   (WCHUNK * WSTR)

__global__ __launch_bounds__(256, 6) void backproject_kernel(const float* __restrict__ filt,
                                                             const float* __restrict__ ws,
                                                             float* __restrict__ out) {
    __shared__ __attribute__((aligned(16))) float2 win[4][WREG];
    __shared__ float cstbuf[WCHUNK];

    const int tid  = threadIdx.x;
    const int bidx = (int)blockIdx.x;
    const int sixth = bidx >> 8;           // 0..5: angle range
    const int rem  = bidx & 255;
    const int b    = (rem >> 6) * 8;       // batches b .. b+7
    const int tile = rem & 63;             // 8 x 8 tiles of 32x32
    const int i0 = (tile >> 3) * 32;
    const int j0 = (tile & 7) * 32;

    const float* trig = ws + 512;

    // compute-phase pixel mapping: wave = 16x16 px, lane = 2x2 px patch
    const int w  = tid >> 6;
    const int l  = tid & 63;
    const int wi = (w >> 1) * 16, wj = (w & 1) * 16;
    const int li = l >> 3, lj = l & 7;
    const int pi = i0 + wi + 2 * li;
    const int pj = j0 + wj + 2 * lj;
    const float xi = -1.f + ((float)pi + 0.5f) * DX_F;
    const float yj = -1.f + ((float)pj + 0.5f) * DX_F;

    // staging mapping: 16 threads per angle (sa < WCHUNK, st < 14 active)
    const int sa = tid >> 4;
    const int st = tid & 15;
    const float xlo = -1.f + ((float)i0 + 0.5f) * DX_F;
    const float xhi = xlo + 31.f * DX_F;
    const float ylo = -1.f + ((float)j0 + 0.5f) * DX_F;
    const float yhi = ylo + 31.f * DX_F;

    const float* fb0 = filt + (size_t)b * (NPHI * FSTR);

    float acc[8][2][2];
    #pragma unroll
    for (int bb = 0; bb < 8; ++bb)
        #pragma unroll
        for (int di = 0; di < 2; ++di)
            #pragma unroll
            for (int dj = 0; dj < 2; ++dj) acc[bb][di][dj] = 0.f;

    const int pbeg = sixth * 120;
    for (int p0 = pbeg; p0 < pbeg + 120; p0 += WCHUNK) {
        __syncthreads();
        if (sa < WCHUNK && st < 14) {
            const int p = p0 + sa;
            const float4 tg = *(const float4*)&trig[p * 4];
            const float umin = 256.5f + fminf(xlo * tg.x, xhi * tg.x)
                                      + fminf(ylo * tg.y, yhi * tg.y);
            const float b0f = floorf(umin) - 1.f;
            if (st == 0) cstbuf[sa] = 256.5f - b0f;
            const int b0 = (int)b0f;
            const int base  = b0 + 5 * st - 1;
            const int basec = min(base, 506);
            const int s0 = sa * WSTR + (basec - b0 + 1);
            #pragma unroll
            for (int pp = 0; pp < 4; ++pp) {
                const float* rA = fb0 + (size_t)(2 * pp) * (NPHI * FSTR)
                                      + (size_t)p * FSTR + 4 + basec;
                const float* rB = rA + (size_t)(NPHI * FSTR);
                f32x4u a0 = *(const f32x4u*)rA;
                f32x2u a1 = *(const f32x2u*)(rA + 4);
                f32x4u c0 = *(const f32x4u*)rB;
                f32x2u c1 = *(const f32x2u*)(rB + 4);
                float fA[6] = {a0[0], a0[1], a0[2], a0[3], a1[0], a1[1]};
                float fB[6] = {c0[0], c0[1], c0[2], c0[3], c1[0], c1[1]};
                #pragma unroll
                for (int j = 0; j < 5; ++j) {
                    h2 pa = __builtin_amdgcn_cvt_pkrtz(fA[j], fA[j + 1]);
                    h2 pb = __builtin_amdgcn_cvt_pkrtz(fB[j], fB[j + 1]);
                    win[pp][s0 + j] = make_float2(__builtin_bit_cast(float, pa),
                                                  __builtin_bit_cast(float, pb));
                }
            }
        }
        __syncthreads();

        #pragma unroll 2
        for (int a = 0; a < WCHUNK; ++a) {
            const float4 tg = *(const float4*)&trig[(p0 + a) * 4]; // cd,sd,dci,dsj
            const float cst = cstbuf[a];
            const float2* wr = &win[0][a * WSTR];
            const float u00 = xi * tg.x + yj * tg.y + cst;
            #pragma unroll
            for (int di = 0; di < 2; ++di) {
                float u = di ? (u00 + tg.z) : u00;
                #pragma unroll
                for (int dj = 0; dj < 2; ++dj) {
                    float fl = floorf(u);
                    float wv = u - fl;
                    int  ip  = (int)fl;
                    h2   wp  = __builtin_amdgcn_cvt_pkrtz(1.f - wv, wv);
                    float2 s01 = wr[ip];
                    float2 s23 = wr[ip + WREG];
                    float2 s45 = wr[ip + 2 * WREG];
                    float2 s67 = wr[ip + 3 * WREG];
                    acc[0][di][dj] = fdot2f(wp, s01.x, acc[0][di][dj]);
                    acc[1][di][dj] = fdot2f(wp, s01.y, acc[1][di][dj]);
                    acc[2][di][dj] = fdot2f(wp, s23.x, acc[2][di][dj]);
                    acc[3][di][dj] = fdot2f(wp, s23.y, acc[3][di][dj]);
                    acc[4][di][dj] = fdot2f(wp, s45.x, acc[4][di][dj]);
                    acc[5][di][dj] = fdot2f(wp, s45.y, acc[5][di][dj]);
                    acc[6][di][dj] = fdot2f(wp, s67.x, acc[6][di][dj]);
                    acc[7][di][dj] = fdot2f(wp, s67.y, acc[7][di][dj]);
                    u += tg.w;
                }
            }
        }
    }

    #pragma unroll
    for (int bb = 0; bb < 8; ++bb) {
        float* ob = out + (size_t)(b + bb) * (NH * NH) + (size_t)pi * NH + pj;
        #pragma unroll
        for (int di = 0; di < 2; ++di)
            #pragma unroll
            for (int dj = 0; dj < 2; ++dj)
                unsafeAtomicAdd(ob + di * NH + dj, acc[bb][di][dj] * DPHI_F);
    }
}

// ---------------------------------------------------------------------------
extern "C" void kernel_launch(void* const* d_in, const int* in_sizes, int n_in,
                              void* d_out, int out_size, void* d_ws, size_t ws_size,
                              hipStream_t stream) {
    const float* sinos = (const float*)d_in[0];   // [32,720,512] f32
    const float* kern  = (const float*)d_in[1];   // [257] f32
    float* out = (float*)d_out;                   // [32,256,256] f32
    float* ws  = (float*)d_ws;

    // ws layout: [0,4096) f32 tables; then padded filt f32 (23040x520 = 47.9MB)
    float* filt = ws + 4096;

    hipLaunchKernelGGL(front_kernel, dim3(490), dim3(512), 0, stream,
                       sinos, kern, ws, (float4*)out, filt);
    hipLaunchKernelGGL(backproject_kernel, dim3(6 * (NB / 8) * 64), dim3(256), 0, stream,
                       filt, ws, out);
}

// Round 17
// 183.503 us; speedup vs baseline: 1.1306x; 1.0795x over previous
//
#include <hip/hip_runtime.h>
#include <hip/hip_bf16.h>

// Geometry constants
#define NPHI 720
#define NT   512
#define NH   256
#define NB   32

#define DPHI_F   0.004363323129985824f   // pi/720
#define INV_DT_F 181.01933598375618f     // 256/sqrt(2)
#define DX_F     0.0078125f              // 2/256
#define W2PI_F   0.012271846303085130f   // 2*pi/512

#define FSTR 520   // padded filt row stride (4 zero | 512 data | 4 zero)

typedef __fp16  h2   __attribute__((ext_vector_type(2)));   // cvt_pkrtz return type
typedef _Float16 f16x2 __attribute__((ext_vector_type(2))); // fdot2 operand type
typedef _Float16 f16x8 __attribute__((ext_vector_type(8))); // mfma A/B operand
typedef float    f32x4 __attribute__((ext_vector_type(4))); // mfma C/D
typedef float    f32x4u __attribute__((ext_vector_type(4), aligned(4)));
typedef float    f32x2u __attribute__((ext_vector_type(2), aligned(4)));

__device__ __forceinline__ float fdot2f(h2 a, float b_bits, float c) {
    return __builtin_amdgcn_fdot2(__builtin_bit_cast(f16x2, a),
                                  __builtin_bit_cast(f16x2, b_bits), c, false);
}

// ---------------------------------------------------------------------------
// Front kernel (R16-measured, verbatim): GEMM filtering + all setup.
//  blocks [0,360):   GEMM 64(M) x 512(N) x 32(K), circulant B built ONCE in
//                    LDS from locally-computed h; A staged per k-step.
//  blocks [360,362): trig table   [362,426): zero out   [426,490): zero pads
// ---------------------------------------------------------------------------
#define ASTR 40
#define BSTR 40

__global__ __launch_bounds__(512) void front_kernel(const float* __restrict__ g,
                                                    const float* __restrict__ kern,
                                                    float* __restrict__ ws,
                                                    float4* __restrict__ out4,
                                                    float* __restrict__ filt) {
    __shared__ __attribute__((aligned(16))) unsigned short As[64 * ASTR];   // 5.12 KB
    __shared__ __attribute__((aligned(16))) unsigned short Bs[512 * BSTR];  // 40 KB
    __shared__ float hloc[512];
    const int bid = (int)blockIdx.x;
    const int tid = threadIdx.x;

    if (bid < 360) {
        // ---- prologue: h = irfft(K,512), then circulant Bs (once) ----
        float* ctab = (float*)As;        // 2 KB alias, dead after prologue
        float* kkp  = (float*)Bs;        // 1 KB alias, dead after prologue
        if (tid < 257) kkp[tid] = kern[tid];
        ctab[tid] = cosf((float)tid * W2PI_F);
        __syncthreads();
        {
            float acc = 0.f;
            for (int k = 1; k < 256; ++k)
                acc += kkp[k] * ctab[(k * tid) & 511];
            hloc[tid] = (kkp[0] + ((tid & 1) ? -kkp[256] : kkp[256]) + 2.f * acc)
                        * (1.f / 512.f);
        }
        __syncthreads();
        {   // Bs row d = tid: Bs[d][m] = h[(d-m)&511], packed fp16 pairs
            unsigned int uu[16];
            #pragma unroll
            for (int q = 0; q < 16; ++q) {
                float lo = hloc[(tid - 2 * q) & 511];
                float hi = hloc[(tid - 2 * q - 1) & 511];
                h2 p = __builtin_amdgcn_cvt_pkrtz(lo, hi);
                uu[q] = __builtin_bit_cast(unsigned int, p);
            }
            unsigned int* dst = (unsigned int*)&Bs[tid * BSTR];
            *(uint4*)(dst)      = make_uint4(uu[0], uu[1], uu[2], uu[3]);
            *(uint4*)(dst + 4)  = make_uint4(uu[4], uu[5], uu[6], uu[7]);
            *(uint4*)(dst + 8)  = make_uint4(uu[8], uu[9], uu[10], uu[11]);
            *(uint4*)(dst + 12) = make_uint4(uu[12], uu[13], uu[14], uu[15]);
        }

        // ---- GEMM ----
        const int m0 = bid * 64;
        const int w = tid >> 6, l = tid & 63;
        const int wm = (w >> 2) * 32;          // 0 or 32
        const int wn = (w & 3) * 128;          // 0,128,256,384
        const int fr = l & 15, g16 = l >> 4;
        const int arow = tid >> 3, aq = (tid & 7) * 4;

        f32x4 acc[2][8];
        #pragma unroll
        for (int i = 0; i < 2; ++i)
            #pragma unroll
            for (int j = 0; j < 8; ++j) acc[i][j] = (f32x4){0.f, 0.f, 0.f, 0.f};

        for (int k0 = 0; k0 < 512; k0 += 32) {
            __syncthreads();
            {   // stage A: 64 rows x 32 fp16
                const float* src = g + (size_t)(m0 + arow) * NT + (k0 + aq);
                float4 v = *(const float4*)src;
                h2 p0 = __builtin_amdgcn_cvt_pkrtz(v.x, v.y);
                h2 p1 = __builtin_amdgcn_cvt_pkrtz(v.z, v.w);
                *(uint2*)&As[arow * ASTR + aq] =
                    make_uint2(__builtin_bit_cast(unsigned int, p0),
                               __builtin_bit_cast(unsigned int, p1));
            }
            __syncthreads();

            f16x8 af[2], bf[8];
            #pragma unroll
            for (int i = 0; i < 2; ++i)
                af[i] = *(const f16x8*)&As[(wm + i * 16 + fr) * ASTR + g16 * 8];
            const int rbase = (wn + fr - k0) & 511;
            #pragma unroll
            for (int j = 0; j < 8; ++j) {
                const int row = (rbase + j * 16) & 511;
                bf[j] = *(const f16x8*)&Bs[row * BSTR + g16 * 8];
            }
            #pragma unroll
            for (int i = 0; i < 2; ++i)
                #pragma unroll
                for (int j = 0; j < 8; ++j)
                    acc[i][j] = __builtin_amdgcn_mfma_f32_16x16x32_f16(af[i], bf[j], acc[i][j], 0, 0, 0);
        }

        #pragma unroll
        for (int i = 0; i < 2; ++i)
            #pragma unroll
            for (int j = 0; j < 8; ++j)
                #pragma unroll
                for (int v = 0; v < 4; ++v) {
                    int row = m0 + wm + i * 16 + g16 * 4 + v;
                    int col = wn + j * 16 + fr;
                    filt[(size_t)row * FSTR + 4 + col] = acc[i][j][v];
                }
    } else if (bid < 362) {
        int p = (bid - 360) * 512 + tid;
        if (p < NPHI) {
            float ang = ((float)p + 0.5f) * DPHI_F;
            float s, c;
            sincosf(ang, &s, &c);
            float cd = c * INV_DT_F;
            float sd = s * INV_DT_F;
            ws[512 + 4 * p + 0] = cd;
            ws[512 + 4 * p + 1] = sd;
            ws[512 + 4 * p + 2] = cd * DX_F;
            ws[512 + 4 * p + 3] = sd * DX_F;
        }
    } else if (bid < 426) {
        const float4 z = make_float4(0.f, 0.f, 0.f, 0.f);
        const int nout4 = NB * NH * NH / 4;            // 524288
        for (int i = (bid - 362) * 512 + tid; i < nout4; i += 64 * 512)
            out4[i] = z;
    } else {
        const float4 z = make_float4(0.f, 0.f, 0.f, 0.f);
        const int nslots = 23040 * 2;                  // 46080
        for (int i = (bid - 426) * 512 + tid; i < nslots; i += 64 * 512) {
            int row = i >> 1;
            float* p = filt + (size_t)row * FSTR + ((i & 1) ? 516 : 0);
            *(float4*)p = z;
        }
    }
}

// ---------------------------------------------------------------------------
// Kernel C: backprojection v11 -- 8 batches/block + T14 async-STAGE split.
// Grid = 6 angle-sixths x 4 batch-octs x 64 tiles = 1536 blocks.
// WCHUNK=8; staging spread over ALL 256 threads: sa=tid>>5 (8 angles),
// sg=(tid>>4)&1 (batch half: 0..3 / 4..7), st=tid&15 (<14 active) -> 24
// landing f32/thread.  Loop: {barrier; WRITE_LDS(c); barrier;
// LOADREGS(c+1); COMPUTE(c)} -- global-load latency hides under compute.
// win[pp][a*WSTR+s] = {lo,hi of batch 2pp | 2pp+1} fp16 (8B); one address
// serves 4 ds_read_b64 (compile-time region offsets) = 8 samples.
// Index convention (R1/R3/R4-verified): ip = floor(q + cst), cst = 256.5-b0.
// ---------------------------------------------------------------------------
#define WCHUNK 8
#define WSTR   82
#define WREG   (WCHUNK * WSTR)

__global__ __launch_bounds__(256, 6) void backproject_kernel(const float* __restrict__ filt,
                                                             const float* __restrict__ ws,
                                                             float* __restrict__ out) {
    __shared__ __attribute__((aligned(16))) float2 win[4][WREG];   // 21 KB
    __shared__ float cstbuf[WCHUNK];

    const int tid  = threadIdx.x;
    const int bidx = (int)blockIdx.x;
    const int sixth = bidx >> 8;           // 0..5: angle range
    const int rem  = bidx & 255;
    const int b    = (rem >> 6) * 8;       // batches b .. b+7
    const int tile = rem & 63;             // 8 x 8 tiles of 32x32
    const int i0 = (tile >> 3) * 32;
    const int j0 = (tile & 7) * 32;

    const float* trig = ws + 512;

    // compute-phase pixel mapping: wave = 16x16 px, lane = 2x2 px patch
    const int w  = tid >> 6;
    const int l  = tid & 63;
    const int wi = (w >> 1) * 16, wj = (w & 1) * 16;
    const int li = l >> 3, lj = l & 7;
    const int pi = i0 + wi + 2 * li;
    const int pj = j0 + wj + 2 * lj;
    const float xi = -1.f + ((float)pi + 0.5f) * DX_F;
    const float yj = -1.f + ((float)pj + 0.5f) * DX_F;

    // staging mapping: 8 angles x 2 batch-halves x 14 threads
    const int sa = tid >> 5;               // angle in chunk
    const int sq = tid & 31;
    const int sg = sq >> 4;                // batch half
    const int st = sq & 15;                // segment, <14 active
    const bool sact = (st < 14);
    const float xlo = -1.f + ((float)i0 + 0.5f) * DX_F;
    const float xhi = xlo + 31.f * DX_F;
    const float ylo = -1.f + ((float)j0 + 0.5f) * DX_F;
    const float yhi = ylo + 31.f * DX_F;

    const float* fb0 = filt + (size_t)b * (NPHI * FSTR);

    float acc[8][2][2];
    #pragma unroll
    for (int bb = 0; bb < 8; ++bb)
        #pragma unroll
        for (int di = 0; di < 2; ++di)
            #pragma unroll
            for (int dj = 0; dj < 2; ++dj) acc[bb][di][dj] = 0.f;

    // staging state (landing registers)
    float fst[4][6];                       // streams: pr0A, pr0B, pr1A, pr1B
    float b0reg = 0.f;
    int   s0reg = 0;

    auto LOADREGS = [&](int p0c) {
        if (!sact) return;
        const int p = p0c + sa;
        const float4 tg = *(const float4*)&trig[p * 4];
        const float umin = 256.5f + fminf(xlo * tg.x, xhi * tg.x)
                                  + fminf(ylo * tg.y, yhi * tg.y);
        const float b0f = floorf(umin) - 1.f;
        b0reg = b0f;
        const int b0 = (int)b0f;
        const int base  = b0 + 5 * st - 1;
        const int basec = min(base, 506);
        s0reg = sa * WSTR + (basec - b0 + 1);
        #pragma unroll
        for (int pr = 0; pr < 2; ++pr) {
            const float* rA = fb0 + (size_t)(4 * sg + 2 * pr) * (NPHI * FSTR)
                                  + (size_t)p * FSTR + 4 + basec;
            const float* rB = rA + (size_t)(NPHI * FSTR);
            f32x4u a0 = *(const f32x4u*)rA;
            f32x2u a1 = *(const f32x2u*)(rA + 4);
            f32x4u c0 = *(const f32x4u*)rB;
            f32x2u c1 = *(const f32x2u*)(rB + 4);
            fst[2*pr+0][0] = a0[0]; fst[2*pr+0][1] = a0[1]; fst[2*pr+0][2] = a0[2];
            fst[2*pr+0][3] = a0[3]; fst[2*pr+0][4] = a1[0]; fst[2*pr+0][5] = a1[1];
            fst[2*pr+1][0] = c0[0]; fst[2*pr+1][1] = c0[1]; fst[2*pr+1][2] = c0[2];
            fst[2*pr+1][3] = c0[3]; fst[2*pr+1][4] = c1[0]; fst[2*pr+1][5] = c1[1];
        }
    };

    auto WRITE_LDS = [&]() {
        if (!sact) return;
        if (st == 0 && sg == 0) cstbuf[sa] = 256.5f - b0reg;
        #pragma unroll
        for (int pr = 0; pr < 2; ++pr) {
            #pragma unroll
            for (int j = 0; j < 5; ++j) {
                h2 pa = __builtin_amdgcn_cvt_pkrtz(fst[2*pr+0][j], fst[2*pr+0][j+1]);
                h2 pb = __builtin_amdgcn_cvt_pkrtz(fst[2*pr+1][j], fst[2*pr+1][j+1]);
                win[2 * sg + pr][s0reg + j] =
                    make_float2(__builtin_bit_cast(float, pa),
                                __builtin_bit_cast(float, pb));
            }
        }
    };

    const int pbeg = sixth * 120;
    LOADREGS(pbeg);
    for (int c = 0; c < 15; ++c) {
        __syncthreads();                   // win free (prev compute done)
        WRITE_LDS();
        __syncthreads();
        if (c + 1 < 15) LOADREGS(pbeg + (c + 1) * WCHUNK);   // issue early

        const int p0 = pbeg + c * WCHUNK;
        #pragma unroll 2
        for (int a = 0; a < WCHUNK; ++a) {
            const float4 tg = *(const float4*)&trig[(p0 + a) * 4]; // cd,sd,dci,dsj
            const float cst = cstbuf[a];
            const float2* wr = &win[0][a * WSTR];
            const float u00 = xi * tg.x + yj * tg.y + cst;
            #pragma unroll
            for (int di = 0; di < 2; ++di) {
                float u = di ? (u00 + tg.z) : u00;
                #pragma unroll
                for (int dj = 0; dj < 2; ++dj) {
                    float fl = floorf(u);
                    float wv = u - fl;
                    int  ip  = (int)fl;
                    h2   wp  = __builtin_amdgcn_cvt_pkrtz(1.f - wv, wv);
                    float2 s01 = wr[ip];
                    float2 s23 = wr[ip + WREG];
                    float2 s45 = wr[ip + 2 * WREG];
                    float2 s67 = wr[ip + 3 * WREG];
                    acc[0][di][dj] = fdot2f(wp, s01.x, acc[0][di][dj]);
                    acc[1][di][dj] = fdot2f(wp, s01.y, acc[1][di][dj]);
                    acc[2][di][dj] = fdot2f(wp, s23.x, acc[2][di][dj]);
                    acc[3][di][dj] = fdot2f(wp, s23.y, acc[3][di][dj]);
                    acc[4][di][dj] = fdot2f(wp, s45.x, acc[4][di][dj]);
                    acc[5][di][dj] = fdot2f(wp, s45.y, acc[5][di][dj]);
                    acc[6][di][dj] = fdot2f(wp, s67.x, acc[6][di][dj]);
                    acc[7][di][dj] = fdot2f(wp, s67.y, acc[7][di][dj]);
                    u += tg.w;
                }
            }
        }
    }

    #pragma unroll
    for (int bb = 0; bb < 8; ++bb) {
        float* ob = out + (size_t)(b + bb) * (NH * NH) + (size_t)pi * NH + pj;
        #pragma unroll
        for (int di = 0; di < 2; ++di)
            #pragma unroll
            for (int dj = 0; dj < 2; ++dj)
                unsafeAtomicAdd(ob + di * NH + dj, acc[bb][di][dj] * DPHI_F);
    }
}

// ---------------------------------------------------------------------------
extern "C" void kernel_launch(void* const* d_in, const int* in_sizes, int n_in,
                              void* d_out, int out_size, void* d_ws, size_t ws_size,
                              hipStream_t stream) {
    const float* sinos = (const float*)d_in[0];   // [32,720,512] f32
    const float* kern  = (const float*)d_in[1];   // [257] f32
    float* out = (float*)d_out;                   // [32,256,256] f32
    float* ws  = (float*)d_ws;

    // ws layout: [0,4096) f32 tables; then padded filt f32 (23040x520 = 47.9MB)
    float* filt = ws + 4096;

    hipLaunchKernelGGL(front_kernel, dim3(490), dim3(512), 0, stream,
                       sinos, kern, ws, (float4*)out, filt);
    hipLaunchKernelGGL(backproject_kernel, dim3(6 * (NB / 8) * 64), dim3(256), 0, stream,
                       filt, ws, out);
}